// Round 2
// 449.709 us; speedup vs baseline: 1.0065x; 1.0065x over previous
//
#include <hip/hip_runtime.h>
#include <cstdint>
#include <cstddef>

#define TOPK 700
#define NPIX 4096   // 64*64
#define NG 4
#define NE 8
#define NW 36       // (E+1)*G

// ---------------------------------------------------------------------------
// Kernel A: sigmoid + exact top-700 (jax.lax.top_k order: value desc, index asc)
// Rank-by-counting on sortable u64 keys: (float_bits(sigmoid) << 12) | (4095-i).
// 64 blocks/batch, 256 thr; 4 threads per element each scan 1/4 of the keys.
// ---------------------------------------------------------------------------
__global__ __launch_bounds__(256) void topk_kernel(
    const float* __restrict__ logits,
    int* __restrict__ sel_idx,
    float* __restrict__ scores_out) {
  __shared__ __attribute__((aligned(16))) unsigned long long keys[NPIX];

  const int b   = blockIdx.x >> 6;   // 64 blocks per batch
  const int blk = blockIdx.x & 63;
  const float* src = logits + b * NPIX;

  for (int i = threadIdx.x; i < NPIX; i += 256) {
    float x = src[i];
    float s = 1.0f / (1.0f + expf(-x));           // precise expf for stable ordering
    keys[i] = (((unsigned long long)__float_as_uint(s)) << 12)
              | (unsigned long long)(4095 - i);    // tie-break: lower index = larger key
  }
  __syncthreads();

  const int e = blk * 64 + (threadIdx.x >> 2);     // element this group of 4 owns
  const int q = threadIdx.x & 3;                   // quarter of the scan
  const unsigned long long mykey = keys[e];

  const ulonglong2* k2 = (const ulonglong2*)keys;  // 2048 pairs
  int rank = 0;
  const int base = q * 512;
  #pragma unroll 8
  for (int jj = 0; jj < 512; ++jj) {
    ulonglong2 kk = k2[base + jj];
    rank += (kk.x > mykey);
    rank += (kk.y > mykey);
  }
  rank += __shfl_xor(rank, 1);
  rank += __shfl_xor(rank, 2);

  if (q == 0 && rank < TOPK) {
    int idx = 4095 - (int)(mykey & 0xFFFULL);
    sel_idx[b * TOPK + rank]    = idx;
    scores_out[b * TOPK + rank] = __uint_as_float((unsigned)(mykey >> 12));
  }
}

// ---------------------------------------------------------------------------
// Kernel B (restructured): 4 blocks per (b,k). Each block builds an 18-row
// halo'd strip (input rows 16q-1 .. 16q+16, edge-clamped CONTENT stored, so
// phase 2 needs no clamping) of the 64-wide sigmoid-product tile in LDS, then
// writes output rows 64q .. 64q+63 of the bilinear 256x256 upsample.
//  - 4.5 KB LDS tile (was 16.4 KB), 4x blocks -> better balance/overlap
//  - phase 2 row-carry: r1 of iter i == r0 of iter i+1 -> 3 LDS reads/iter
// ---------------------------------------------------------------------------
__global__ __launch_bounds__(256) void mask_kernel(
    const float* __restrict__ enc,       // [B, 8, 4096]
    const float* __restrict__ weights,   // [B, 36, 4096]
    const int* __restrict__ sel_idx,     // [B*700]
    float* __restrict__ out_m) {         // [B*700, 256, 256]
  __shared__ float ws[NW];
  __shared__ __attribute__((aligned(16))) float tile[18 * 64];  // 4.5 KB

  const int blk = blockIdx.x;            // 0..5599
  const int bk  = blk >> 2;              // 0..1399
  const int qs  = blk & 3;               // strip index: out rows [64qs, 64qs+63]
  const int b   = (bk >= TOPK) ? 1 : 0;
  const int tid = threadIdx.x;

  const int p = sel_idx[bk];             // selected pixel (h*64+w), uniform
  if (tid < NW) ws[tid] = weights[(size_t)(b * NW + tid) * NPIX + p];
  __syncthreads();

  float wreg[NW];
  #pragma unroll
  for (int c = 0; c < NW; ++c) wreg[c] = ws[c];   // LDS broadcast, once

  // ---- phase 1: strip rows g = row0+j, j in [0,18); clamped content ----
  const int row0 = qs * 16 - 1;
  const float* eb = enc + (size_t)b * NE * NPIX;

  // 288 float4-quads: pass 0 = quads 0..255 (all threads),
  // pass 1 = quads 256..287 (tid < 32). quad qq -> row j=qq>>4, col4=(qq&15)*4
  #pragma unroll
  for (int pass = 0; pass < 2; ++pass) {
    if (pass == 0 || tid < 32) {
      const int qq   = tid + pass * 256;
      const int j    = qq >> 4;
      const int col4 = (qq & 15) << 2;
      const int g    = row0 + j;
      const int gc   = (g < 0) ? 0 : ((g > 63) ? 63 : g);
      const int src4 = gc * 64 + col4;
      float4 ev[NE];
      #pragma unroll
      for (int ch = 0; ch < NE; ++ch)
        ev[ch] = *(const float4*)(eb + (size_t)ch * NPIX + src4);
      float4 s = make_float4(1.f, 1.f, 1.f, 1.f);
      #pragma unroll
      for (int g2 = 0; g2 < NG; ++g2) {
        float zx = wreg[g2 * 9 + 8], zy = zx, zz = zx, zw = zx;  // bias
        #pragma unroll
        for (int ch = 0; ch < NE; ++ch) {
          float w = wreg[g2 * 9 + ch];
          zx = fmaf(w, ev[ch].x, zx);
          zy = fmaf(w, ev[ch].y, zy);
          zz = fmaf(w, ev[ch].z, zz);
          zw = fmaf(w, ev[ch].w, zw);
        }
        s.x *= __builtin_amdgcn_rcpf(1.f + __expf(-zx));
        s.y *= __builtin_amdgcn_rcpf(1.f + __expf(-zy));
        s.z *= __builtin_amdgcn_rcpf(1.f + __expf(-zz));
        s.w *= __builtin_amdgcn_rcpf(1.f + __expf(-zw));
      }
      *(float4*)(&tile[j * 64 + col4]) = s;
    }
  }
  __syncthreads();

  // ---- phase 2: bilinear, out rows 64qs+ty+4i, i in [0,16) ----
  // in_y = (oy+0.5)/4 - 0.5 = 16qs + i + (ty*0.25 - 0.375); halo rows already
  // hold clamped content, so local rows are simply jbase+i / jbase+i+1.
  const int tx = tid & 63;
  const int ty = tid >> 6;

  const int cxm = (tx > 0) ? tx - 1 : 0;
  const int cxp = (tx < 63) ? tx + 1 : 63;

  const float base_y = ty * 0.25f - 0.375f;
  const float fy0 = floorf(base_y);             // -1 (ty<2) or 0 (ty>=2)
  const float wy  = base_y - fy0;               // 0.625,0.875,0.125,0.375
  const int jbase = (ty < 2) ? 0 : 1;           // fy0 + 1 (local row of y0 at i=0)

  float* orow = out_m + (size_t)bk * 65536 + (size_t)(qs * 64 + ty) * 256 + 4 * tx;

  // row-carry: a* = row y0 of current iter; read only row y1 each iter.
  const float* r0 = &tile[jbase * 64];
  float am = r0[cxm], a0 = r0[tx], ap = r0[cxp];

  #pragma unroll 4
  for (int i = 0; i < 16; ++i) {
    const float* r1 = &tile[(jbase + i + 1) * 64];
    float bm = r1[cxm], b0 = r1[tx], bp = r1[cxp];
    float vm = fmaf(wy, bm - am, am);
    float v0 = fmaf(wy, b0 - a0, a0);
    float vp = fmaf(wy, bp - ap, ap);
    float4 o;
    o.x = vm * 0.375f + v0 * 0.625f;   // ox=4tx+0: frac 0.625 from col tx-1
    o.y = vm * 0.125f + v0 * 0.875f;   // ox=4tx+1
    o.z = v0 * 0.875f + vp * 0.125f;   // ox=4tx+2
    o.w = v0 * 0.625f + vp * 0.375f;   // ox=4tx+3
    *(float4*)(orow + (size_t)i * 1024) = o;    // row oy = 64qs + ty + 4i
    am = bm; a0 = b0; ap = bp;
  }
}

extern "C" void kernel_launch(void* const* d_in, const int* in_sizes, int n_in,
                              void* d_out, int out_size, void* d_ws, size_t ws_size,
                              hipStream_t stream) {
  const float* logits  = (const float*)d_in[0];  // (2,1,64,64)
  const float* enc     = (const float*)d_in[1];  // (2,8,64,64)
  const float* weights = (const float*)d_in[2];  // (2,36,64,64)

  float* out        = (float*)d_out;
  float* out_m      = out;                                    // 2*700*256*256
  float* out_scores = out + (size_t)2 * TOPK * 256 * 256;     // 2*700
  int*   sel_idx    = (int*)d_ws;                             // 2*700 ints

  topk_kernel<<<128, 256, 0, stream>>>(logits, sel_idx, out_scores);
  mask_kernel<<<4 * 2 * TOPK, 256, 0, stream>>>(enc, weights, sel_idx, out_m);
}

// Round 4
// 394.618 us; speedup vs baseline: 1.1470x; 1.1396x over previous
//
#include <hip/hip_runtime.h>
#include <cstdint>
#include <cstddef>

#define TOPK 700
#define NPIX 4096   // 64*64
#define NG 4
#define NE 8
#define NW 36       // (E+1)*G

typedef float nt_float4 __attribute__((ext_vector_type(4)));  // native vec for nt store

// ---------------------------------------------------------------------------
// Kernel A: sigmoid + exact top-700 (jax.lax.top_k order: value desc, index asc)
// Rank-by-counting on sortable u64 keys: (float_bits(sigmoid) << 12) | (4095-i).
// 64 blocks/batch, 256 thr; 4 threads per element each scan 1/4 of the keys.
// ---------------------------------------------------------------------------
__global__ __launch_bounds__(256) void topk_kernel(
    const float* __restrict__ logits,
    int* __restrict__ sel_idx,
    float* __restrict__ scores_out) {
  __shared__ __attribute__((aligned(16))) unsigned long long keys[NPIX];

  const int b   = blockIdx.x >> 6;   // 64 blocks per batch
  const int blk = blockIdx.x & 63;
  const float* src = logits + b * NPIX;

  for (int i = threadIdx.x; i < NPIX; i += 256) {
    float x = src[i];
    float s = 1.0f / (1.0f + expf(-x));           // precise expf for stable ordering
    keys[i] = (((unsigned long long)__float_as_uint(s)) << 12)
              | (unsigned long long)(4095 - i);    // tie-break: lower index = larger key
  }
  __syncthreads();

  const int e = blk * 64 + (threadIdx.x >> 2);     // element this group of 4 owns
  const int q = threadIdx.x & 3;                   // quarter of the scan
  const unsigned long long mykey = keys[e];

  const ulonglong2* k2 = (const ulonglong2*)keys;  // 2048 pairs
  int rank = 0;
  const int base = q * 512;
  #pragma unroll 8
  for (int jj = 0; jj < 512; ++jj) {
    ulonglong2 kk = k2[base + jj];
    rank += (kk.x > mykey);
    rank += (kk.y > mykey);
  }
  rank += __shfl_xor(rank, 1);
  rank += __shfl_xor(rank, 2);

  if (q == 0 && rank < TOPK) {
    int idx = 4095 - (int)(mykey & 0xFFFULL);
    sel_idx[b * TOPK + rank]    = idx;
    scores_out[b * TOPK + rank] = __uint_as_float((unsigned)(mykey >> 12));
  }
}

// ---------------------------------------------------------------------------
// Kernel B: 4 blocks per (b,k). Each block builds an 18-row halo'd strip
// (input rows 16q-1 .. 16q+16, edge-clamped CONTENT stored) of the 64-wide
// sigmoid-product tile in LDS, then writes output rows 64q..64q+63 of the
// bilinear 256x256 upsample.
// R4 change (isolated, = R3 intent): out_m stores are NONTEMPORAL (nt hint)
// via clang ext_vector_type (HIP float4 is rejected by the builtin). Bypasses
// the L2 dirty-allocate/evict path for the 367 MB streaming output. Values
// are bit-identical to the verified R2 kernel.
// ---------------------------------------------------------------------------
__global__ __launch_bounds__(256) void mask_kernel(
    const float* __restrict__ enc,       // [B, 8, 4096]
    const float* __restrict__ weights,   // [B, 36, 4096]
    const int* __restrict__ sel_idx,     // [B*700]
    float* __restrict__ out_m) {         // [B*700, 256, 256]
  __shared__ float ws[NW];
  __shared__ __attribute__((aligned(16))) float tile[18 * 64];  // 4.5 KB

  const int blk = blockIdx.x;            // 0..5599
  const int bk  = blk >> 2;              // 0..1399
  const int qs  = blk & 3;               // strip index: out rows [64qs, 64qs+63]
  const int b   = (bk >= TOPK) ? 1 : 0;
  const int tid = threadIdx.x;

  const int p = sel_idx[bk];             // selected pixel (h*64+w), uniform
  if (tid < NW) ws[tid] = weights[(size_t)(b * NW + tid) * NPIX + p];
  __syncthreads();

  float wreg[NW];
  #pragma unroll
  for (int c = 0; c < NW; ++c) wreg[c] = ws[c];   // LDS broadcast, once

  // ---- phase 1: strip rows g = row0+j, j in [0,18); clamped content ----
  const int row0 = qs * 16 - 1;
  const float* eb = enc + (size_t)b * NE * NPIX;

  // 288 float4-quads: pass 0 = quads 0..255 (all threads),
  // pass 1 = quads 256..287 (tid < 32). quad qq -> row j=qq>>4, col4=(qq&15)*4
  #pragma unroll
  for (int pass = 0; pass < 2; ++pass) {
    if (pass == 0 || tid < 32) {
      const int qq   = tid + pass * 256;
      const int j    = qq >> 4;
      const int col4 = (qq & 15) << 2;
      const int g    = row0 + j;
      const int gc   = (g < 0) ? 0 : ((g > 63) ? 63 : g);
      const int src4 = gc * 64 + col4;
      float4 ev[NE];
      #pragma unroll
      for (int ch = 0; ch < NE; ++ch)
        ev[ch] = *(const float4*)(eb + (size_t)ch * NPIX + src4);
      float4 s = make_float4(1.f, 1.f, 1.f, 1.f);
      #pragma unroll
      for (int g2 = 0; g2 < NG; ++g2) {
        float zx = wreg[g2 * 9 + 8], zy = zx, zz = zx, zw = zx;  // bias
        #pragma unroll
        for (int ch = 0; ch < NE; ++ch) {
          float w = wreg[g2 * 9 + ch];
          zx = fmaf(w, ev[ch].x, zx);
          zy = fmaf(w, ev[ch].y, zy);
          zz = fmaf(w, ev[ch].z, zz);
          zw = fmaf(w, ev[ch].w, zw);
        }
        s.x *= __builtin_amdgcn_rcpf(1.f + __expf(-zx));
        s.y *= __builtin_amdgcn_rcpf(1.f + __expf(-zy));
        s.z *= __builtin_amdgcn_rcpf(1.f + __expf(-zz));
        s.w *= __builtin_amdgcn_rcpf(1.f + __expf(-zw));
      }
      *(float4*)(&tile[j * 64 + col4]) = s;
    }
  }
  __syncthreads();

  // ---- phase 2: bilinear, out rows 64qs+ty+4i, i in [0,16) ----
  // in_y = (oy+0.5)/4 - 0.5 = 16qs + i + (ty*0.25 - 0.375); halo rows already
  // hold clamped content, so local rows are simply jbase+i / jbase+i+1.
  const int tx = tid & 63;
  const int ty = tid >> 6;

  const int cxm = (tx > 0) ? tx - 1 : 0;
  const int cxp = (tx < 63) ? tx + 1 : 63;

  const float base_y = ty * 0.25f - 0.375f;
  const float fy0 = floorf(base_y);             // -1 (ty<2) or 0 (ty>=2)
  const float wy  = base_y - fy0;               // 0.625,0.875,0.125,0.375
  const int jbase = (ty < 2) ? 0 : 1;           // fy0 + 1 (local row of y0 at i=0)

  float* orow = out_m + (size_t)bk * 65536 + (size_t)(qs * 64 + ty) * 256 + 4 * tx;

  // row-carry: a* = row y0 of current iter; read only row y1 each iter.
  const float* r0 = &tile[jbase * 64];
  float am = r0[cxm], a0 = r0[tx], ap = r0[cxp];

  #pragma unroll 4
  for (int i = 0; i < 16; ++i) {
    const float* r1 = &tile[(jbase + i + 1) * 64];
    float bm = r1[cxm], b0 = r1[tx], bp = r1[cxp];
    float vm = fmaf(wy, bm - am, am);
    float v0 = fmaf(wy, b0 - a0, a0);
    float vp = fmaf(wy, bp - ap, ap);
    nt_float4 o;
    o.x = vm * 0.375f + v0 * 0.625f;   // ox=4tx+0: frac 0.625 from col tx-1
    o.y = vm * 0.125f + v0 * 0.875f;   // ox=4tx+1
    o.z = v0 * 0.875f + vp * 0.125f;   // ox=4tx+2
    o.w = v0 * 0.625f + vp * 0.375f;   // ox=4tx+3
    __builtin_nontemporal_store(o, (nt_float4*)(orow + (size_t)i * 1024)); // nt store
    am = bm; a0 = b0; ap = bp;
  }
}

extern "C" void kernel_launch(void* const* d_in, const int* in_sizes, int n_in,
                              void* d_out, int out_size, void* d_ws, size_t ws_size,
                              hipStream_t stream) {
  const float* logits  = (const float*)d_in[0];  // (2,1,64,64)
  const float* enc     = (const float*)d_in[1];  // (2,8,64,64)
  const float* weights = (const float*)d_in[2];  // (2,36,64,64)

  float* out        = (float*)d_out;
  float* out_m      = out;                                    // 2*700*256*256
  float* out_scores = out + (size_t)2 * TOPK * 256 * 256;     // 2*700
  int*   sel_idx    = (int*)d_ws;                             // 2*700 ints

  topk_kernel<<<128, 256, 0, stream>>>(logits, sel_idx, out_scores);
  mask_kernel<<<4 * 2 * TOPK, 256, 0, stream>>>(enc, weights, sel_idx, out_m);
}